// Round 1
// baseline (4148.257 us; speedup 1.0000x reference)
//
#include <hip/hip_runtime.h>
#include <hip/hip_bf16.h>

#define NN 65536
#define SS 128
#define CC 128
#define EE 262144
#define BB 512
#define LL 3

// ---------------- column stats (sum, sumsq) over N rows ----------------
__global__ __launch_bounds__(256) void colstats128(const float* __restrict__ in,
                                                   float* __restrict__ stats) {
    const int tid = threadIdx.x;
    const int c = tid & 127;
    const int rh = tid >> 7;  // 0/1
    float s = 0.f, sq = 0.f;
    for (int r = blockIdx.x * 2 + rh; r < NN; r += gridDim.x * 2) {
        float v = in[(size_t)r * 128 + c];
        s += v; sq += v * v;
    }
    __shared__ float ls[256], lq[256];
    ls[tid] = s; lq[tid] = sq;
    __syncthreads();
    if (tid < 128) {
        atomicAdd(&stats[c], ls[tid] + ls[tid + 128]);
        atomicAdd(&stats[128 + c], lq[tid] + lq[tid + 128]);
    }
}

__global__ __launch_bounds__(256) void colstats_pe(const float* __restrict__ pe,
                                                   float* __restrict__ stats) {
    const int c = blockIdx.x;   // 0..19
    const int tid = threadIdx.x;
    float s = 0.f, sq = 0.f;
    for (int r = tid; r < NN; r += 256) {
        float v = pe[(size_t)r * 20 + c];
        s += v; sq += v * v;
    }
    __shared__ float ls[256], lq[256];
    ls[tid] = s; lq[tid] = sq;
    __syncthreads();
    for (int w = 128; w > 0; w >>= 1) {
        if (tid < w) { ls[tid] += ls[tid + w]; lq[tid] += lq[tid + w]; }
        __syncthreads();
    }
    if (tid == 0) { stats[c] = ls[0]; stats[20 + c] = lq[0]; }
}

// scale = g*rsqrt(var+eps); off = b - mean*scale
__global__ void bn_finalize(const float* __restrict__ stats, const float* __restrict__ g,
                            const float* __restrict__ b, float* __restrict__ scoff,
                            int ncols, float invn) {
    const int c = threadIdx.x;
    if (c < ncols) {
        float m = stats[c] * invn;
        float var = stats[ncols + c] * invn - m * m;
        float rs = rsqrtf(var + 1e-5f);
        float sc = g[c] * rs;
        scoff[c] = sc;
        scoff[ncols + c] = b[c] - m * sc;
    }
}

// out = in*scale + off  (+ addin)
template <int ADD>
__global__ __launch_bounds__(256) void bn_apply(const float* __restrict__ in,
                                                const float* __restrict__ scoff,
                                                const float* __restrict__ addin,
                                                float* __restrict__ out) {
    const size_t i = (size_t)blockIdx.x * 256 + threadIdx.x;
    const int c = (int)(i & 127);
    float v = in[i] * scoff[c] + scoff[128 + c];
    if (ADD) v += addin[i];
    out[i] = v;
}

__global__ __launch_bounds__(256) void add_k(const float* __restrict__ a,
                                             const float* __restrict__ b,
                                             float* __restrict__ out) {
    const size_t i = (size_t)blockIdx.x * 256 + threadIdx.x;
    out[i] = a[i] + b[i];
}

// ---------------- input featurization ----------------
__global__ __launch_bounds__(256) void embed_kernel(const int* __restrict__ node_type,
                                                    const float* __restrict__ pe,
                                                    const float* __restrict__ scoff,
                                                    const float* __restrict__ peW,
                                                    const float* __restrict__ peB,
                                                    const float* __restrict__ node_emb,
                                                    float* __restrict__ X) {
    const size_t i = (size_t)blockIdx.x * 256 + threadIdx.x;
    const int n = (int)(i >> 7), c = (int)(i & 127);
    float v;
    if (c < 120) {
        v = node_emb[(size_t)node_type[n] * 120 + c];
    } else {
        const int j = c - 120;
        float acc = peB[j];
#pragma unroll
        for (int k = 0; k < 20; ++k) {
            float p = pe[(size_t)n * 20 + k] * scoff[k] + scoff[20 + k];
            acc = fmaf(p, peW[k * 8 + j], acc);
        }
        v = acc;
    }
    X[i] = v;
}

// ---------------- GINE message + scatter-add ----------------
__global__ __launch_bounds__(256) void gine_scatter(const float* __restrict__ X,
                                                    const int* __restrict__ eidx,
                                                    const int* __restrict__ etype,
                                                    const float* __restrict__ edge_emb,
                                                    float* __restrict__ agg) {
    const int t = blockIdx.x * 256 + threadIdx.x;  // EE*32 threads
    const int e = t >> 5;
    const int cg = (t & 31) << 2;
    if (e >= EE) return;
    const int src = eidx[e];
    const int dst = eidx[EE + e];
    const int et = etype[e];
    const float4 xv = *(const float4*)&X[(size_t)src * 128 + cg];
    const float4 ev = *(const float4*)&edge_emb[(size_t)et * 128 + cg];
    float4 m;
    m.x = fmaxf(xv.x + ev.x, 0.f);
    m.y = fmaxf(xv.y + ev.y, 0.f);
    m.z = fmaxf(xv.z + ev.z, 0.f);
    m.w = fmaxf(xv.w + ev.w, 0.f);
    float* d = &agg[(size_t)dst * 128 + cg];
    atomicAdd(d + 0, m.x);
    atomicAdd(d + 1, m.y);
    atomicAdd(d + 2, m.z);
    atomicAdd(d + 3, m.w);
}

// ---------------- tiled fp32 GEMM: out = act(A@W + bias [+ resid]) ----------------
// A:[N,K] W:[K,M] bias:[M] resid:[N,M]; BM=BN=64, BK=32, 256 thr, 4x4/thread
template <int RELU, int RESID>
__global__ __launch_bounds__(256) void gemm_k(const float* __restrict__ A,
                                              const float* __restrict__ W,
                                              const float* __restrict__ bias,
                                              const float* __restrict__ resid,
                                              float* __restrict__ out, int K, int M) {
    __shared__ float As[64][33];
    __shared__ float Ws[32][65];
    const int bm = blockIdx.x * 64;
    const int bn = blockIdx.y * 64;
    const int tid = threadIdx.x;
    const int tr = tid >> 4, tc = tid & 15;
    float acc[4][4] = {};
    for (int k0 = 0; k0 < K; k0 += 32) {
#pragma unroll
        for (int i = 0; i < 2; ++i) {
            int t = tid + i * 256;
            int r = t >> 3, c4 = (t & 7) << 2;
            const float4 v = *(const float4*)&A[(size_t)(bm + r) * K + k0 + c4];
            As[r][c4] = v.x; As[r][c4 + 1] = v.y; As[r][c4 + 2] = v.z; As[r][c4 + 3] = v.w;
        }
#pragma unroll
        for (int i = 0; i < 2; ++i) {
            int t = tid + i * 256;
            int r = t >> 4, c4 = (t & 15) << 2;
            const float4 v = *(const float4*)&W[(size_t)(k0 + r) * M + bn + c4];
            Ws[r][c4] = v.x; Ws[r][c4 + 1] = v.y; Ws[r][c4 + 2] = v.z; Ws[r][c4 + 3] = v.w;
        }
        __syncthreads();
#pragma unroll
        for (int kk = 0; kk < 32; ++kk) {
            float a[4], b[4];
#pragma unroll
            for (int i = 0; i < 4; ++i) a[i] = As[tr * 4 + i][kk];
#pragma unroll
            for (int j = 0; j < 4; ++j) b[j] = Ws[kk][tc * 4 + j];
#pragma unroll
            for (int i = 0; i < 4; ++i)
#pragma unroll
                for (int j = 0; j < 4; ++j) acc[i][j] = fmaf(a[i], b[j], acc[i][j]);
        }
        __syncthreads();
    }
#pragma unroll
    for (int i = 0; i < 4; ++i) {
        const int row = bm + tr * 4 + i;
#pragma unroll
        for (int j = 0; j < 4; ++j) {
            const int col = bn + tc * 4 + j;
            float v = acc[i][j] + bias[col];
            if (RESID) v += resid[(size_t)row * M + col];
            if (RELU) v = fmaxf(v, 0.f);
            out[(size_t)row * M + col] = v;
        }
    }
}

// ---------------- per-(graph, head) attention ----------------
// qkv: [N, 384] row = [q(2x64) | k(2x64) | v(2x64)]; o: [N, 128]
__global__ __launch_bounds__(256) void attn_k(const float* __restrict__ qkv,
                                              float* __restrict__ o) {
    __shared__ float sc[128][129];
    const int b = blockIdx.x >> 1;
    const int hh = blockIdx.x & 1;
    const int tid = threadIdx.x;
    const float* base = qkv + (size_t)b * SS * 384;
    const float* qb = base + hh * 64;
    const float* kb = base + 128 + hh * 64;
    const float* vb = base + 256 + hh * 64;
    const int tr = tid >> 4, tc = tid & 15;
    {   // scores = q @ k^T * scale : each thread 8x8
        float acc[8][8] = {};
        for (int d = 0; d < 64; ++d) {
            float qv[8], kv[8];
#pragma unroll
            for (int i = 0; i < 8; ++i) qv[i] = qb[(tr * 8 + i) * 384 + d];
#pragma unroll
            for (int j = 0; j < 8; ++j) kv[j] = kb[(tc * 8 + j) * 384 + d];
#pragma unroll
            for (int i = 0; i < 8; ++i)
#pragma unroll
                for (int j = 0; j < 8; ++j) acc[i][j] = fmaf(qv[i], kv[j], acc[i][j]);
        }
#pragma unroll
        for (int i = 0; i < 8; ++i)
#pragma unroll
            for (int j = 0; j < 8; ++j) sc[tr * 8 + i][tc * 8 + j] = acc[i][j] * 0.125f;
    }
    __syncthreads();
    {   // row softmax: 2 threads per row, combine via shfl_xor(1)
        const int row = tid >> 1;
        const int half = (tid & 1) * 64;
        float m = -1e30f;
        for (int j = 0; j < 64; ++j) m = fmaxf(m, sc[row][half + j]);
        m = fmaxf(m, __shfl_xor(m, 1));
        float s = 0.f;
        for (int j = 0; j < 64; ++j) {
            float p = __expf(sc[row][half + j] - m);
            sc[row][half + j] = p;
            s += p;
        }
        s += __shfl_xor(s, 1);
        const float inv = 1.f / s;
        for (int j = 0; j < 64; ++j) sc[row][half + j] *= inv;
    }
    __syncthreads();
    {   // O = P @ V : each thread 8 rows x 4 cols
        float acc[8][4] = {};
        for (int jj = 0; jj < 128; ++jj) {
            float pv[8];
#pragma unroll
            for (int i = 0; i < 8; ++i) pv[i] = sc[tr * 8 + i][jj];
            float vv[4];
#pragma unroll
            for (int j = 0; j < 4; ++j) vv[j] = vb[jj * 384 + tc * 4 + j];
#pragma unroll
            for (int i = 0; i < 8; ++i)
#pragma unroll
                for (int j = 0; j < 4; ++j) acc[i][j] = fmaf(pv[i], vv[j], acc[i][j]);
        }
#pragma unroll
        for (int i = 0; i < 8; ++i) {
            const int row = tr * 8 + i;
#pragma unroll
            for (int j = 0; j < 4; ++j)
                o[((size_t)b * 128 + row) * 128 + hh * 64 + tc * 4 + j] = acc[i][j];
        }
    }
}

extern "C" void kernel_launch(void* const* d_in, const int* in_sizes, int n_in,
                              void* d_out, int out_size, void* d_ws, size_t ws_size,
                              hipStream_t stream) {
    const int* node_type = (const int*)d_in[0];
    const float* pe = (const float*)d_in[1];
    const int* eidx = (const int*)d_in[2];
    const int* etype = (const int*)d_in[3];
    // d_in[4] = batch (implicit, unused)
    const float* pe_gamma = (const float*)d_in[5];
    const float* pe_beta = (const float*)d_in[6];
    const float* pe_W = (const float*)d_in[7];
    const float* pe_b = (const float*)d_in[8];
    const float* node_emb = (const float*)d_in[9];
    const float* edge_emb = (const float*)d_in[10];
    const float* gine_W1 = (const float*)d_in[11];
    const float* gine_b1 = (const float*)d_in[12];
    const float* gine_W2 = (const float*)d_in[13];
    const float* gine_b2 = (const float*)d_in[14];
    const float* n1_g = (const float*)d_in[15];
    const float* n1_b = (const float*)d_in[16];
    const float* n2_g = (const float*)d_in[17];
    const float* n2_b = (const float*)d_in[18];
    const float* n3_g = (const float*)d_in[19];
    const float* n3_b = (const float*)d_in[20];
    const float* attn_inW = (const float*)d_in[21];
    const float* attn_inb = (const float*)d_in[22];
    const float* attn_outW = (const float*)d_in[23];
    const float* attn_outb = (const float*)d_in[24];
    const float* mlp_W1 = (const float*)d_in[25];
    const float* mlp_b1 = (const float*)d_in[26];
    const float* mlp_W2 = (const float*)d_in[27];
    const float* mlp_b2 = (const float*)d_in[28];

    float* X = (float*)d_out;  // persistent node features [N,128]; final BN lands here
    float* ws = (float*)d_ws;
    const size_t NC = (size_t)NN * CC;
    float* AGG = ws;                 // [N,128]
    float* Z = AGG + NC;             // [N,128]
    float* H = Z + NC;               // [N,128]
    float* R = H + NC;               // [N,384] (qkv; later out | t2)
    float* STATS = R + (size_t)NN * 384;  // 768
    float* SCOFF = STATS + 768;           // 768

    const int EW = NN * CC / 256;  // elementwise grid
    const dim3 g128(NN / 64, 128 / 64);
    const dim3 g256(NN / 64, 256 / 64);
    const dim3 g384(NN / 64, 384 / 64);
    const float invn = 1.f / (float)NN;

    // ---- input featurization ----
    colstats_pe<<<20, 256, 0, stream>>>(pe, STATS);
    bn_finalize<<<1, 64, 0, stream>>>(STATS, pe_gamma, pe_beta, SCOFF, 20, invn);
    embed_kernel<<<EW, 256, 0, stream>>>(node_type, pe, SCOFF, pe_W, pe_b, node_emb, X);

    for (int l = 0; l < LL; ++l) {
        const float* gW1 = gine_W1 + (size_t)l * CC * CC;
        const float* gb1 = gine_b1 + (size_t)l * CC;
        const float* gW2 = gine_W2 + (size_t)l * CC * CC;
        const float* gb2 = gine_b2 + (size_t)l * CC;
        const float* inW = attn_inW + (size_t)l * CC * 384;
        const float* inb = attn_inb + (size_t)l * 384;
        const float* oW = attn_outW + (size_t)l * CC * CC;
        const float* ob = attn_outb + (size_t)l * CC;
        const float* mW1 = mlp_W1 + (size_t)l * CC * 256;
        const float* mb1 = mlp_b1 + (size_t)l * 256;
        const float* mW2 = mlp_W2 + (size_t)l * 256 * CC;
        const float* mb2 = mlp_b2 + (size_t)l * CC;

        // ---- GINEConv ----
        hipMemsetAsync(AGG, 0, NC * sizeof(float), stream);
        gine_scatter<<<EE * 32 / 256, 256, 0, stream>>>(X, eidx, etype, edge_emb, AGG);
        add_k<<<EW, 256, 0, stream>>>(X, AGG, Z);                     // z = x + agg
        gemm_k<1, 0><<<g128, 256, 0, stream>>>(Z, gW1, gb1, nullptr, R, 128, 128);  // t1
        gemm_k<0, 1><<<g128, 256, 0, stream>>>(R, gW2, gb2, X, Z, 128, 128);        // h_pre
        hipMemsetAsync(STATS, 0, 256 * sizeof(float), stream);
        colstats128<<<512, 256, 0, stream>>>(Z, STATS);
        bn_finalize<<<1, 128, 0, stream>>>(STATS, n1_g + l * CC, n1_b + l * CC, SCOFF, 128, invn);
        bn_apply<0><<<EW, 256, 0, stream>>>(Z, SCOFF, nullptr, H);    // h

        // ---- attention ----
        gemm_k<0, 0><<<g384, 256, 0, stream>>>(X, inW, inb, nullptr, R, 128, 384);  // qkv
        attn_k<<<BB * 2, 256, 0, stream>>>(R, Z);                                   // o
        gemm_k<0, 1><<<g128, 256, 0, stream>>>(Z, oW, ob, X, AGG, 128, 128);        // ha_pre
        hipMemsetAsync(STATS, 0, 256 * sizeof(float), stream);
        colstats128<<<512, 256, 0, stream>>>(AGG, STATS);
        bn_finalize<<<1, 128, 0, stream>>>(STATS, n2_g + l * CC, n2_b + l * CC, SCOFF, 128, invn);
        bn_apply<1><<<EW, 256, 0, stream>>>(AGG, SCOFF, H, R);        // out = bn(ha)+h -> R[0:NC]

        // ---- FFN ----
        gemm_k<1, 0><<<g256, 256, 0, stream>>>(R, mW1, mb1, nullptr, R + NC, 128, 256);  // t2
        gemm_k<0, 1><<<g128, 256, 0, stream>>>(R + NC, mW2, mb2, R, Z, 256, 128);        // out2
        hipMemsetAsync(STATS, 0, 256 * sizeof(float), stream);
        colstats128<<<512, 256, 0, stream>>>(Z, STATS);
        bn_finalize<<<1, 128, 0, stream>>>(STATS, n3_g + l * CC, n3_b + l * CC, SCOFF, 128, invn);
        bn_apply<0><<<EW, 256, 0, stream>>>(Z, SCOFF, nullptr, X);    // x = bn(out2)
    }
}

// Round 2
// 2265.144 us; speedup vs baseline: 1.8313x; 1.8313x over previous
//
#include <hip/hip_runtime.h>
#include <hip/hip_bf16.h>

#define NN 65536
#define SS 128
#define CC 128
#define EE 262144
#define BB 512
#define LL 3

// ================= CSR build =================
__global__ __launch_bounds__(256) void hist_k(const int* __restrict__ eidx,
                                              int* __restrict__ cnt) {
    const int e = blockIdx.x * 256 + threadIdx.x;
    atomicAdd(&cnt[eidx[EE + e]], 1);
}

// per-256-chunk exclusive scan, chunk totals to part[]
__global__ __launch_bounds__(256) void scan1_k(const int* __restrict__ cnt,
                                               int* __restrict__ row,
                                               int* __restrict__ part) {
    __shared__ int s[256];
    const int tid = threadIdx.x;
    const int i = blockIdx.x * 256 + tid;
    const int v = cnt[i];
    s[tid] = v;
    __syncthreads();
    for (int off = 1; off < 256; off <<= 1) {
        int t = (tid >= off) ? s[tid - off] : 0;
        __syncthreads();
        s[tid] += t;
        __syncthreads();
    }
    row[i] = s[tid] - v;
    if (tid == 255) part[blockIdx.x] = s[255];
}

__global__ __launch_bounds__(256) void scan2_k(int* __restrict__ part) {
    __shared__ int s[256];
    const int tid = threadIdx.x;
    const int v = part[tid];
    s[tid] = v;
    __syncthreads();
    for (int off = 1; off < 256; off <<= 1) {
        int t = (tid >= off) ? s[tid - off] : 0;
        __syncthreads();
        s[tid] += t;
        __syncthreads();
    }
    part[tid] = s[tid] - v;
}

__global__ __launch_bounds__(256) void scan3_k(int* __restrict__ row,
                                               const int* __restrict__ part) {
    const int i = blockIdx.x * 256 + threadIdx.x;
    row[i] += part[blockIdx.x];
    if (i == 0) row[NN] = EE;
}

__global__ __launch_bounds__(256) void fill_k(const int* __restrict__ eidx,
                                              const int* __restrict__ row,
                                              int* __restrict__ cnt,
                                              int* __restrict__ elist) {
    const int e = blockIdx.x * 256 + threadIdx.x;
    const int d = eidx[EE + e];
    const int slot = row[d] + atomicAdd(&cnt[d], 1);
    elist[slot] = e;
}

// ================= GINE gather: Z = X + sum relu(X[src]+ee) =================
__global__ __launch_bounds__(256) void gine_gather(const float* __restrict__ X,
                                                   const int* __restrict__ eidx,
                                                   const int* __restrict__ etype,
                                                   const float* __restrict__ edge_emb,
                                                   const int* __restrict__ row,
                                                   const int* __restrict__ elist,
                                                   float* __restrict__ Z) {
    const int n = blockIdx.x * 8 + (threadIdx.x >> 5);
    const int c4 = (threadIdx.x & 31) << 2;
    const int beg = row[n], end = row[n + 1];
    float4 z = *(const float4*)&X[(size_t)n * 128 + c4];
    for (int j = beg; j < end; ++j) {
        const int e = elist[j];
        const int s = eidx[e];
        const int et = etype[e];
        const float4 xv = *(const float4*)&X[(size_t)s * 128 + c4];
        const float4 ev = *(const float4*)&edge_emb[(size_t)et * 128 + c4];
        z.x += fmaxf(xv.x + ev.x, 0.f);
        z.y += fmaxf(xv.y + ev.y, 0.f);
        z.z += fmaxf(xv.z + ev.z, 0.f);
        z.w += fmaxf(xv.w + ev.w, 0.f);
    }
    *(float4*)&Z[(size_t)n * 128 + c4] = z;
}

// ================= BN helpers =================
__global__ __launch_bounds__(256) void colstats_pe(const float* __restrict__ pe,
                                                   float* __restrict__ stats) {
    const int c = blockIdx.x;
    const int tid = threadIdx.x;
    float s = 0.f, sq = 0.f;
    for (int r = tid; r < NN; r += 256) {
        float v = pe[(size_t)r * 20 + c];
        s += v; sq += v * v;
    }
    __shared__ float ls[256], lq[256];
    ls[tid] = s; lq[tid] = sq;
    __syncthreads();
    for (int w = 128; w > 0; w >>= 1) {
        if (tid < w) { ls[tid] += ls[tid + w]; lq[tid] += lq[tid + w]; }
        __syncthreads();
    }
    if (tid == 0) { stats[c] = ls[0]; stats[20 + c] = lq[0]; }
}

__global__ void bn_finalize(const float* __restrict__ stats, const float* __restrict__ g,
                            const float* __restrict__ b, float* __restrict__ scoff,
                            int ncols, float invn) {
    const int c = threadIdx.x;
    if (c < ncols) {
        float m = stats[c] * invn;
        float var = stats[ncols + c] * invn - m * m;
        float rs = rsqrtf(var + 1e-5f);
        float sc = g[c] * rs;
        scoff[c] = sc;
        scoff[ncols + c] = b[c] - m * sc;
    }
}

__global__ __launch_bounds__(256) void bn_apply(const float* __restrict__ in,
                                                const float* __restrict__ scoff,
                                                float* __restrict__ out) {
    const size_t i = (size_t)blockIdx.x * 256 + threadIdx.x;
    const int c = (int)(i & 127);
    out[i] = in[i] * scoff[c] + scoff[128 + c];
}

// out = bn1(hpre) + bn2(hapre)
__global__ __launch_bounds__(256) void combine2(const float* __restrict__ hpre,
                                                const float* __restrict__ hapre,
                                                const float* __restrict__ scoff,
                                                float* __restrict__ out) {
    const size_t i = (size_t)blockIdx.x * 256 + threadIdx.x;
    const int c = (int)(i & 127);
    out[i] = hpre[i] * scoff[c] + scoff[128 + c] +
             hapre[i] * scoff[256 + c] + scoff[384 + c];
}

// ================= input featurization =================
__global__ __launch_bounds__(256) void embed_kernel(const int* __restrict__ node_type,
                                                    const float* __restrict__ pe,
                                                    const float* __restrict__ scoff,
                                                    const float* __restrict__ peW,
                                                    const float* __restrict__ peB,
                                                    const float* __restrict__ node_emb,
                                                    float* __restrict__ X) {
    const size_t i = (size_t)blockIdx.x * 256 + threadIdx.x;
    const int n = (int)(i >> 7), c = (int)(i & 127);
    float v;
    if (c < 120) {
        v = node_emb[(size_t)node_type[n] * 120 + c];
    } else {
        const int j = c - 120;
        float acc = peB[j];
#pragma unroll
        for (int k = 0; k < 20; ++k) {
            float p = pe[(size_t)n * 20 + k] * scoff[k] + scoff[20 + k];
            acc = fmaf(p, peW[k * 8 + j], acc);
        }
        v = acc;
    }
    X[i] = v;
}

// ================= tiled fp32 GEMM 128x128, 8x8/thread =================
// out = act(A@W + bias [+ resid]); optional column stats (sum,sumsq) -> atomics
template <int RELU, int RESID, int STATS>
__global__ __launch_bounds__(256) void gemm_k(const float* __restrict__ A,
                                              const float* __restrict__ W,
                                              const float* __restrict__ bias,
                                              const float* __restrict__ resid,
                                              float* __restrict__ out, int K, int M,
                                              float* __restrict__ stats) {
    __shared__ float As[128 * 36];   // [row][k] pad to 36
    __shared__ float Ws[32 * 136];   // [k][col] pad to 136
    const int bm = blockIdx.x * 128;
    const int bn = blockIdx.y * 128;
    const int tid = threadIdx.x;
    const int tr = tid >> 4, tc = tid & 15;
    float acc[8][8] = {};
    for (int k0 = 0; k0 < K; k0 += 32) {
#pragma unroll
        for (int i = 0; i < 4; ++i) {
            const int f = tid + i * 256;
            const int r = f >> 3, c4 = (f & 7) << 2;
            const float4 v = *(const float4*)&A[(size_t)(bm + r) * K + k0 + c4];
            *(float4*)&As[r * 36 + c4] = v;
        }
#pragma unroll
        for (int i = 0; i < 4; ++i) {
            const int f = tid + i * 256;
            const int r = f >> 5, c4 = (f & 31) << 2;
            const float4 v = *(const float4*)&W[(size_t)(k0 + r) * M + bn + c4];
            *(float4*)&Ws[r * 136 + c4] = v;
        }
        __syncthreads();
#pragma unroll
        for (int k4 = 0; k4 < 8; ++k4) {
            float av[8][4];
#pragma unroll
            for (int i = 0; i < 8; ++i) {
                const float4 t = *(const float4*)&As[(tr * 8 + i) * 36 + k4 * 4];
                av[i][0] = t.x; av[i][1] = t.y; av[i][2] = t.z; av[i][3] = t.w;
            }
#pragma unroll
            for (int r = 0; r < 4; ++r) {
                const float4 t0 = *(const float4*)&Ws[(k4 * 4 + r) * 136 + tc * 8];
                const float4 t1 = *(const float4*)&Ws[(k4 * 4 + r) * 136 + tc * 8 + 4];
                float bv[8] = {t0.x, t0.y, t0.z, t0.w, t1.x, t1.y, t1.z, t1.w};
#pragma unroll
                for (int i = 0; i < 8; ++i)
#pragma unroll
                    for (int j = 0; j < 8; ++j)
                        acc[i][j] = fmaf(av[i][r], bv[j], acc[i][j]);
            }
        }
        __syncthreads();
    }
    // epilogue
    float vsum[8], vsq[8];
#pragma unroll
    for (int j = 0; j < 8; ++j) { vsum[j] = 0.f; vsq[j] = 0.f; }
    const int colb = bn + tc * 8;
    float bv0[8];
#pragma unroll
    for (int j = 0; j < 8; ++j) bv0[j] = bias[colb + j];
#pragma unroll
    for (int i = 0; i < 8; ++i) {
        const int rrow = bm + tr * 8 + i;
        float v[8];
#pragma unroll
        for (int j = 0; j < 8; ++j) v[j] = acc[i][j] + bv0[j];
        if (RESID) {
            const float4 r0 = *(const float4*)&resid[(size_t)rrow * M + colb];
            const float4 r1 = *(const float4*)&resid[(size_t)rrow * M + colb + 4];
            v[0] += r0.x; v[1] += r0.y; v[2] += r0.z; v[3] += r0.w;
            v[4] += r1.x; v[5] += r1.y; v[6] += r1.z; v[7] += r1.w;
        }
        if (RELU) {
#pragma unroll
            for (int j = 0; j < 8; ++j) v[j] = fmaxf(v[j], 0.f);
        }
        if (STATS) {
#pragma unroll
            for (int j = 0; j < 8; ++j) { vsum[j] += v[j]; vsq[j] += v[j] * v[j]; }
        }
        float4 o0 = {v[0], v[1], v[2], v[3]};
        float4 o1 = {v[4], v[5], v[6], v[7]};
        *(float4*)&out[(size_t)rrow * M + colb] = o0;
        *(float4*)&out[(size_t)rrow * M + colb + 4] = o1;
    }
    if (STATS) {
        __syncthreads();  // done with As/Ws staging
        float* reds = As;           // [16][128]
        float* redq = Ws;           // [16][128]
#pragma unroll
        for (int j = 0; j < 8; ++j) {
            reds[tr * 128 + tc * 8 + j] = vsum[j];
            redq[tr * 128 + tc * 8 + j] = vsq[j];
        }
        __syncthreads();
        if (tid < 128) {
            float s = 0.f, q = 0.f;
#pragma unroll
            for (int t = 0; t < 16; ++t) { s += reds[t * 128 + tid]; q += redq[t * 128 + tid]; }
            atomicAdd(&stats[tid], s);
            atomicAdd(&stats[128 + tid], q);
        }
    }
}

// ================= per-(graph, head) attention =================
__global__ __launch_bounds__(256) void attn_k(const float* __restrict__ qkv,
                                              float* __restrict__ o) {
    __shared__ float sc[128][129];
    const int b = blockIdx.x >> 1;
    const int hh = blockIdx.x & 1;
    const int tid = threadIdx.x;
    const float* base = qkv + (size_t)b * SS * 384;
    const float* qb = base + hh * 64;
    const float* kb = base + 128 + hh * 64;
    const float* vb = base + 256 + hh * 64;
    const int tr = tid >> 4, tc = tid & 15;
    {
        float acc[8][8] = {};
        for (int d = 0; d < 64; ++d) {
            float qv[8], kv[8];
#pragma unroll
            for (int i = 0; i < 8; ++i) qv[i] = qb[(tr * 8 + i) * 384 + d];
#pragma unroll
            for (int j = 0; j < 8; ++j) kv[j] = kb[(tc * 8 + j) * 384 + d];
#pragma unroll
            for (int i = 0; i < 8; ++i)
#pragma unroll
                for (int j = 0; j < 8; ++j) acc[i][j] = fmaf(qv[i], kv[j], acc[i][j]);
        }
#pragma unroll
        for (int i = 0; i < 8; ++i)
#pragma unroll
            for (int j = 0; j < 8; ++j) sc[tr * 8 + i][tc * 8 + j] = acc[i][j] * 0.125f;
    }
    __syncthreads();
    {
        const int row = tid >> 1;
        const int half = (tid & 1) * 64;
        float m = -1e30f;
        for (int j = 0; j < 64; ++j) m = fmaxf(m, sc[row][half + j]);
        m = fmaxf(m, __shfl_xor(m, 1));
        float s = 0.f;
        for (int j = 0; j < 64; ++j) {
            float p = __expf(sc[row][half + j] - m);
            sc[row][half + j] = p;
            s += p;
        }
        s += __shfl_xor(s, 1);
        const float inv = 1.f / s;
        for (int j = 0; j < 64; ++j) sc[row][half + j] *= inv;
    }
    __syncthreads();
    {
        float acc[8][4] = {};
        for (int jj = 0; jj < 128; ++jj) {
            float pv[8];
#pragma unroll
            for (int i = 0; i < 8; ++i) pv[i] = sc[tr * 8 + i][jj];
            float vv[4];
#pragma unroll
            for (int j = 0; j < 4; ++j) vv[j] = vb[jj * 384 + tc * 4 + j];
#pragma unroll
            for (int i = 0; i < 8; ++i)
#pragma unroll
                for (int j = 0; j < 4; ++j) acc[i][j] = fmaf(pv[i], vv[j], acc[i][j]);
        }
#pragma unroll
        for (int i = 0; i < 8; ++i) {
            const int row = tr * 8 + i;
#pragma unroll
            for (int j = 0; j < 4; ++j)
                o[((size_t)b * 128 + row) * 128 + hh * 64 + tc * 4 + j] = acc[i][j];
        }
    }
}

extern "C" void kernel_launch(void* const* d_in, const int* in_sizes, int n_in,
                              void* d_out, int out_size, void* d_ws, size_t ws_size,
                              hipStream_t stream) {
    const int* node_type = (const int*)d_in[0];
    const float* pe = (const float*)d_in[1];
    const int* eidx = (const int*)d_in[2];
    const int* etype = (const int*)d_in[3];
    const float* pe_gamma = (const float*)d_in[5];
    const float* pe_beta = (const float*)d_in[6];
    const float* pe_W = (const float*)d_in[7];
    const float* pe_b = (const float*)d_in[8];
    const float* node_emb = (const float*)d_in[9];
    const float* edge_emb = (const float*)d_in[10];
    const float* gine_W1 = (const float*)d_in[11];
    const float* gine_b1 = (const float*)d_in[12];
    const float* gine_W2 = (const float*)d_in[13];
    const float* gine_b2 = (const float*)d_in[14];
    const float* n1_g = (const float*)d_in[15];
    const float* n1_b = (const float*)d_in[16];
    const float* n2_g = (const float*)d_in[17];
    const float* n2_b = (const float*)d_in[18];
    const float* n3_g = (const float*)d_in[19];
    const float* n3_b = (const float*)d_in[20];
    const float* attn_inW = (const float*)d_in[21];
    const float* attn_inb = (const float*)d_in[22];
    const float* attn_outW = (const float*)d_in[23];
    const float* attn_outb = (const float*)d_in[24];
    const float* mlp_W1 = (const float*)d_in[25];
    const float* mlp_b1 = (const float*)d_in[26];
    const float* mlp_W2 = (const float*)d_in[27];
    const float* mlp_b2 = (const float*)d_in[28];

    float* X = (float*)d_out;            // persistent node features [N,128]
    float* ws = (float*)d_ws;
    const size_t NC = (size_t)NN * CC;
    float* Z = ws;                       // [N,128] h_pre / out2_pre
    float* O = Z + NC;                   // [N,128] t1 / attn-o / OUT
    float* R = O + NC;                   // [N,384] qkv; later HA=R[0:NC], T2=R[NC:3NC]
    float* HA = R;
    float* T2 = R + NC;
    float* STATS = R + 3 * NC;           // 256
    float* STATS2 = STATS + 256;         // 256
    float* SCOFF = STATS2 + 256;         // 512
    int* icnt = (int*)(SCOFF + 512);     // [N]
    int* irow = icnt + NN;               // [N+1]
    int* ielist = irow + NN + 1;         // [E]
    int* ipart = ielist + EE;            // [256]

    const int EW = NN * CC / 256;
    const dim3 g128(NN / 128, 1);
    const dim3 g256(NN / 128, 2);
    const dim3 g384(NN / 128, 3);
    const float invn = 1.f / (float)NN;

    // ---- CSR build (once; reused by all 3 layers) ----
    hipMemsetAsync(icnt, 0, NN * sizeof(int), stream);
    hist_k<<<EE / 256, 256, 0, stream>>>(eidx, icnt);
    scan1_k<<<NN / 256, 256, 0, stream>>>(icnt, irow, ipart);
    scan2_k<<<1, 256, 0, stream>>>(ipart);
    scan3_k<<<NN / 256, 256, 0, stream>>>(irow, ipart);
    hipMemsetAsync(icnt, 0, NN * sizeof(int), stream);
    fill_k<<<EE / 256, 256, 0, stream>>>(eidx, irow, icnt, ielist);

    // ---- input featurization ----
    colstats_pe<<<20, 256, 0, stream>>>(pe, STATS);
    bn_finalize<<<1, 64, 0, stream>>>(STATS, pe_gamma, pe_beta, SCOFF, 20, invn);
    embed_kernel<<<EW, 256, 0, stream>>>(node_type, pe, SCOFF, pe_W, pe_b, node_emb, X);

    for (int l = 0; l < LL; ++l) {
        const float* gW1 = gine_W1 + (size_t)l * CC * CC;
        const float* gb1 = gine_b1 + (size_t)l * CC;
        const float* gW2 = gine_W2 + (size_t)l * CC * CC;
        const float* gb2 = gine_b2 + (size_t)l * CC;
        const float* inW = attn_inW + (size_t)l * CC * 384;
        const float* inb = attn_inb + (size_t)l * 384;
        const float* oW = attn_outW + (size_t)l * CC * CC;
        const float* ob = attn_outb + (size_t)l * CC;
        const float* mW1 = mlp_W1 + (size_t)l * CC * 256;
        const float* mb1 = mlp_b1 + (size_t)l * 256;
        const float* mW2 = mlp_W2 + (size_t)l * 256 * CC;
        const float* mb2 = mlp_b2 + (size_t)l * CC;

        // ---- GINEConv ----
        gine_gather<<<NN / 8, 256, 0, stream>>>(X, eidx, etype, edge_emb, irow, ielist, Z);
        gemm_k<1, 0, 0><<<g128, 256, 0, stream>>>(Z, gW1, gb1, nullptr, O, 128, 128, nullptr);
        hipMemsetAsync(STATS, 0, 256 * sizeof(float), stream);
        gemm_k<0, 1, 1><<<g128, 256, 0, stream>>>(O, gW2, gb2, X, Z, 128, 128, STATS);
        bn_finalize<<<1, 128, 0, stream>>>(STATS, n1_g + l * CC, n1_b + l * CC, SCOFF, 128, invn);

        // ---- attention ----
        gemm_k<0, 0, 0><<<g384, 256, 0, stream>>>(X, inW, inb, nullptr, R, 128, 384, nullptr);
        attn_k<<<BB * 2, 256, 0, stream>>>(R, O);
        hipMemsetAsync(STATS2, 0, 256 * sizeof(float), stream);
        gemm_k<0, 1, 1><<<g128, 256, 0, stream>>>(O, oW, ob, X, HA, 128, 128, STATS2);
        bn_finalize<<<1, 128, 0, stream>>>(STATS2, n2_g + l * CC, n2_b + l * CC, SCOFF + 256, 128, invn);

        // ---- combine + FFN ----
        combine2<<<EW, 256, 0, stream>>>(Z, HA, SCOFF, O);  // OUT -> O
        gemm_k<1, 0, 0><<<g256, 256, 0, stream>>>(O, mW1, mb1, nullptr, T2, 128, 256, nullptr);
        hipMemsetAsync(STATS, 0, 256 * sizeof(float), stream);
        gemm_k<0, 1, 1><<<g128, 256, 0, stream>>>(T2, mW2, mb2, O, Z, 256, 128, STATS);
        bn_finalize<<<1, 128, 0, stream>>>(STATS, n3_g + l * CC, n3_b + l * CC, SCOFF, 128, invn);
        bn_apply<<<EW, 256, 0, stream>>>(Z, SCOFF, X);
    }
}

// Round 3
// 884.631 us; speedup vs baseline: 4.6892x; 2.5606x over previous
//
#include <hip/hip_runtime.h>
#include <hip/hip_bf16.h>

#define NN 65536
#define SS 128
#define CC 128
#define EE 262144
#define BB 512
#define LL 3

typedef __attribute__((ext_vector_type(8))) short bf16x8;
typedef __attribute__((ext_vector_type(4))) float f32x4;

__device__ __forceinline__ float b2f(unsigned short u) {
    union { unsigned int i; float f; } x; x.i = ((unsigned int)u) << 16; return x.f;
}
__device__ __forceinline__ unsigned short f2b(float f) {
    union { float f; unsigned int i; } x; x.f = f;
    unsigned int r = x.i + 0x7fffu + ((x.i >> 16) & 1u);
    return (unsigned short)(r >> 16);
}
// swizzled byte offset within a tile of row-stride ROWB bytes
#define SWB(row, colbyte, ROWB) ((row) * (ROWB) + ((colbyte) ^ (((row) & 7) << 4)))

// ================= CSR build =================
__global__ __launch_bounds__(256) void hist_k(const int* __restrict__ eidx, int* __restrict__ cnt) {
    const int e = blockIdx.x * 256 + threadIdx.x;
    atomicAdd(&cnt[eidx[EE + e]], 1);
}
__global__ __launch_bounds__(256) void scan1_k(const int* __restrict__ cnt, int* __restrict__ row,
                                               int* __restrict__ part) {
    __shared__ int s[256];
    const int tid = threadIdx.x;
    const int i = blockIdx.x * 256 + tid;
    const int v = cnt[i];
    s[tid] = v;
    __syncthreads();
    for (int off = 1; off < 256; off <<= 1) {
        int t = (tid >= off) ? s[tid - off] : 0;
        __syncthreads(); s[tid] += t; __syncthreads();
    }
    row[i] = s[tid] - v;
    if (tid == 255) part[blockIdx.x] = s[255];
}
__global__ __launch_bounds__(256) void scan2_k(int* __restrict__ part) {
    __shared__ int s[256];
    const int tid = threadIdx.x;
    const int v = part[tid];
    s[tid] = v;
    __syncthreads();
    for (int off = 1; off < 256; off <<= 1) {
        int t = (tid >= off) ? s[tid - off] : 0;
        __syncthreads(); s[tid] += t; __syncthreads();
    }
    part[tid] = s[tid] - v;
}
__global__ __launch_bounds__(256) void scan3_k(int* __restrict__ row, const int* __restrict__ part) {
    const int i = blockIdx.x * 256 + threadIdx.x;
    row[i] += part[blockIdx.x];
    if (i == 0) row[NN] = EE;
}
__global__ __launch_bounds__(256) void fill_k(const int* __restrict__ eidx, const int* __restrict__ row,
                                              int* __restrict__ cnt, int* __restrict__ elist) {
    const int e = blockIdx.x * 256 + threadIdx.x;
    const int d = eidx[EE + e];
    const int slot = row[d] + atomicAdd(&cnt[d], 1);
    elist[slot] = e;
}

// ================= weight convert + transpose to bf16 WT[N][K] =================
__global__ __launch_bounds__(256) void cvtw(const float* __restrict__ gW1, const float* __restrict__ gW2,
                                            const float* __restrict__ inW, const float* __restrict__ oW,
                                            const float* __restrict__ mW1, const float* __restrict__ mW2,
                                            unsigned short* __restrict__ WB) {
    const int g = blockIdx.x * 256 + threadIdx.x;  // 0 .. 3*163840
    const int l = g / 163840;
    const int r = g % 163840;
    const float* src; int K, Nc, dst, i;
    if (r < 16384)       { src = gW1 + l * 16384; K = 128; Nc = 128; dst = 0;      i = r; }
    else if (r < 32768)  { src = gW2 + l * 16384; K = 128; Nc = 128; dst = 16384;  i = r - 16384; }
    else if (r < 81920)  { src = inW + l * 49152; K = 128; Nc = 384; dst = 32768;  i = r - 32768; }
    else if (r < 98304)  { src = oW  + l * 16384; K = 128; Nc = 128; dst = 81920;  i = r - 81920; }
    else if (r < 131072) { src = mW1 + l * 32768; K = 128; Nc = 256; dst = 98304;  i = r - 98304; }
    else                 { src = mW2 + l * 32768; K = 256; Nc = 128; dst = 131072; i = r - 131072; }
    const int k = i / Nc, c = i % Nc;
    WB[(size_t)l * 163840 + dst + (size_t)c * K + k] = f2b(src[i]);
}

// ================= BN helpers =================
__global__ __launch_bounds__(256) void colstats_pe(const float* __restrict__ pe, float* __restrict__ stats) {
    const int c = blockIdx.x;
    const int tid = threadIdx.x;
    float s = 0.f, sq = 0.f;
    for (int r = tid; r < NN; r += 256) {
        float v = pe[(size_t)r * 20 + c];
        s += v; sq += v * v;
    }
    __shared__ float ls[256], lq[256];
    ls[tid] = s; lq[tid] = sq;
    __syncthreads();
    for (int w = 128; w > 0; w >>= 1) {
        if (tid < w) { ls[tid] += ls[tid + w]; lq[tid] += lq[tid + w]; }
        __syncthreads();
    }
    if (tid == 0) { stats[c] = ls[0]; stats[20 + c] = lq[0]; }
}
__global__ void bn_finalize(const float* __restrict__ stats, const float* __restrict__ g,
                            const float* __restrict__ b, float* __restrict__ scoff,
                            int ncols, float invn) {
    const int c = threadIdx.x;
    if (c < ncols) {
        float m = stats[c] * invn;
        float var = stats[ncols + c] * invn - m * m;
        float rs = rsqrtf(var + 1e-5f);
        float sc = g[c] * rs;
        scoff[c] = sc;
        scoff[ncols + c] = b[c] - m * sc;
    }
}
// XB (bf16) <- bn(Z)
__global__ __launch_bounds__(256) void bn_apply_b(const unsigned short* __restrict__ in,
                                                  const float* __restrict__ scoff,
                                                  unsigned short* __restrict__ out) {
    const size_t g = (size_t)blockIdx.x * 256 + threadIdx.x;  // N*16
    const int c8 = ((int)g & 15) << 3;
    union { uint4 u; unsigned short s[8]; } a, o;
    a.u = *(const uint4*)(in + g * 8);
#pragma unroll
    for (int i = 0; i < 8; ++i) o.s[i] = f2b(b2f(a.s[i]) * scoff[c8 + i] + scoff[128 + c8 + i]);
    *(uint4*)(((unsigned short*)out) + g * 8) = o.u;
}
// d_out (f32) <- bn(Z)
__global__ __launch_bounds__(256) void bn_apply_f(const unsigned short* __restrict__ in,
                                                  const float* __restrict__ scoff,
                                                  float* __restrict__ out) {
    const size_t g = (size_t)blockIdx.x * 256 + threadIdx.x;
    const int c8 = ((int)g & 15) << 3;
    union { uint4 u; unsigned short s[8]; } a;
    a.u = *(const uint4*)(in + g * 8);
    float4 o0, o1;
    o0.x = b2f(a.s[0]) * scoff[c8 + 0] + scoff[128 + c8 + 0];
    o0.y = b2f(a.s[1]) * scoff[c8 + 1] + scoff[128 + c8 + 1];
    o0.z = b2f(a.s[2]) * scoff[c8 + 2] + scoff[128 + c8 + 2];
    o0.w = b2f(a.s[3]) * scoff[c8 + 3] + scoff[128 + c8 + 3];
    o1.x = b2f(a.s[4]) * scoff[c8 + 4] + scoff[128 + c8 + 4];
    o1.y = b2f(a.s[5]) * scoff[c8 + 5] + scoff[128 + c8 + 5];
    o1.z = b2f(a.s[6]) * scoff[c8 + 6] + scoff[128 + c8 + 6];
    o1.w = b2f(a.s[7]) * scoff[c8 + 7] + scoff[128 + c8 + 7];
    *(float4*)(out + g * 8) = o0;
    *(float4*)(out + g * 8 + 4) = o1;
}
// OUT = bn1(Z) + bn2(HA)
__global__ __launch_bounds__(256) void combine2(const unsigned short* __restrict__ z,
                                                const unsigned short* __restrict__ ha,
                                                const float* __restrict__ scoff,
                                                unsigned short* __restrict__ out) {
    const size_t g = (size_t)blockIdx.x * 256 + threadIdx.x;
    const int c8 = ((int)g & 15) << 3;
    union { uint4 u; unsigned short s[8]; } a, b, o;
    a.u = *(const uint4*)(z + g * 8);
    b.u = *(const uint4*)(ha + g * 8);
#pragma unroll
    for (int i = 0; i < 8; ++i) {
        const int c = c8 + i;
        o.s[i] = f2b(b2f(a.s[i]) * scoff[c] + scoff[128 + c] +
                     b2f(b.s[i]) * scoff[256 + c] + scoff[384 + c]);
    }
    *(uint4*)(out + g * 8) = o.u;
}

// ================= input featurization -> XB bf16 =================
__global__ __launch_bounds__(256) void embed_b(const int* __restrict__ node_type,
                                               const float* __restrict__ pe,
                                               const float* __restrict__ scoff,
                                               const float* __restrict__ peW,
                                               const float* __restrict__ peB,
                                               const float* __restrict__ node_emb,
                                               unsigned short* __restrict__ XB) {
    const int g = blockIdx.x * 256 + threadIdx.x;  // N*16
    const int n = g >> 4, c8 = (g & 15) << 3;
    float v[8];
    if (c8 < 120) {
        const float4 a = *(const float4*)(node_emb + (size_t)node_type[n] * 120 + c8);
        const float4 b = *(const float4*)(node_emb + (size_t)node_type[n] * 120 + c8 + 4);
        v[0] = a.x; v[1] = a.y; v[2] = a.z; v[3] = a.w;
        v[4] = b.x; v[5] = b.y; v[6] = b.z; v[7] = b.w;
    } else {
#pragma unroll
        for (int j = 0; j < 8; ++j) v[j] = peB[j];
#pragma unroll
        for (int k = 0; k < 20; ++k) {
            const float p = pe[(size_t)n * 20 + k] * scoff[k] + scoff[20 + k];
#pragma unroll
            for (int j = 0; j < 8; ++j) v[j] = fmaf(p, peW[k * 8 + j], v[j]);
        }
    }
    union { uint4 u; unsigned short s[8]; } o;
#pragma unroll
    for (int i = 0; i < 8; ++i) o.s[i] = f2b(v[i]);
    *(uint4*)(XB + (size_t)g * 8) = o.u;
}

// ================= GINE gather: Z = X + sum relu(X[src]+ee)  (bf16) =================
__global__ __launch_bounds__(256) void gine_gather_b(const unsigned short* __restrict__ XB,
                                                     const int* __restrict__ eidx,
                                                     const int* __restrict__ etype,
                                                     const float* __restrict__ edge_emb,
                                                     const int* __restrict__ row,
                                                     const int* __restrict__ elist,
                                                     unsigned short* __restrict__ Z) {
    const int n = blockIdx.x * 16 + (threadIdx.x >> 4);
    const int c8 = (threadIdx.x & 15) << 3;
    const int beg = row[n], end = row[n + 1];
    union { uint4 u; unsigned short s[8]; } x;
    x.u = *(const uint4*)(XB + (size_t)n * 128 + c8);
    float z[8];
#pragma unroll
    for (int i = 0; i < 8; ++i) z[i] = b2f(x.s[i]);
    for (int j = beg; j < end; ++j) {
        const int e = elist[j];
        const int s = eidx[e];
        const int et = etype[e];
        union { uint4 u; unsigned short s[8]; } xs;
        xs.u = *(const uint4*)(XB + (size_t)s * 128 + c8);
        const float4 e0 = *(const float4*)(edge_emb + (size_t)et * 128 + c8);
        const float4 e1 = *(const float4*)(edge_emb + (size_t)et * 128 + c8 + 4);
        z[0] += fmaxf(b2f(xs.s[0]) + e0.x, 0.f);
        z[1] += fmaxf(b2f(xs.s[1]) + e0.y, 0.f);
        z[2] += fmaxf(b2f(xs.s[2]) + e0.z, 0.f);
        z[3] += fmaxf(b2f(xs.s[3]) + e0.w, 0.f);
        z[4] += fmaxf(b2f(xs.s[4]) + e1.x, 0.f);
        z[5] += fmaxf(b2f(xs.s[5]) + e1.y, 0.f);
        z[6] += fmaxf(b2f(xs.s[6]) + e1.z, 0.f);
        z[7] += fmaxf(b2f(xs.s[7]) + e1.w, 0.f);
    }
    union { uint4 u; unsigned short s[8]; } o;
#pragma unroll
    for (int i = 0; i < 8; ++i) o.s[i] = f2b(z[i]);
    *(uint4*)(Z + (size_t)n * 128 + c8) = o.u;
}

// ================= MFMA bf16 GEMM: out[M,Nw] = act(A[M,K] @ WT[Nw,K]^T + bias [+resid]) =================
// 128x128 tile, 4 waves (2x2), 16x16x32 MFMA, XOR-swizzled LDS.
template <int RELU, int RESID, int STATS, int KT>
__global__ __launch_bounds__(256) void gemm_bf(const unsigned short* __restrict__ A,
                                               const unsigned short* __restrict__ WT,
                                               const float* __restrict__ bias,
                                               const unsigned short* __restrict__ resid,
                                               unsigned short* __restrict__ out,
                                               float* __restrict__ stats, int Nw) {
    __shared__ __align__(16) unsigned short As[128 * 128];
    __shared__ __align__(16) unsigned short Bs[128 * 128];
    const int bm = blockIdx.x * 128, bn = blockIdx.y * 128;
    const int tid = threadIdx.x;
    const int lane = tid & 63, w = tid >> 6, wr = w >> 1, wc = w & 1;
    const int lr = lane & 15, lg = lane >> 4;
    const int K = KT * 128;
    f32x4 acc[4][4];
#pragma unroll
    for (int m = 0; m < 4; ++m)
#pragma unroll
        for (int n = 0; n < 4; ++n) acc[m][n] = (f32x4){0.f, 0.f, 0.f, 0.f};

    for (int kt = 0; kt < KT; ++kt) {
        if (kt) __syncthreads();
#pragma unroll
        for (int i = 0; i < 8; ++i) {
            const int f = tid + i * 256;
            const int r = f >> 4, ch = f & 15;
            *(uint4*)((char*)As + SWB(r, ch * 16, 256)) =
                *(const uint4*)(A + (size_t)(bm + r) * K + kt * 128 + ch * 8);
            *(uint4*)((char*)Bs + SWB(r, ch * 16, 256)) =
                *(const uint4*)(WT + (size_t)(bn + r) * K + kt * 128 + ch * 8);
        }
        __syncthreads();
#pragma unroll
        for (int ks = 0; ks < 4; ++ks) {
            bf16x8 af[4], bfr[4];
#pragma unroll
            for (int m = 0; m < 4; ++m) {
                const int row = wr * 64 + m * 16 + lr;
                af[m] = *(const bf16x8*)((const char*)As + SWB(row, ks * 64 + lg * 16, 256));
            }
#pragma unroll
            for (int n = 0; n < 4; ++n) {
                const int row = wc * 64 + n * 16 + lr;
                bfr[n] = *(const bf16x8*)((const char*)Bs + SWB(row, ks * 64 + lg * 16, 256));
            }
#pragma unroll
            for (int m = 0; m < 4; ++m)
#pragma unroll
                for (int n = 0; n < 4; ++n)
                    acc[m][n] = __builtin_amdgcn_mfma_f32_16x16x32_bf16(af[m], bfr[n], acc[m][n], 0, 0, 0);
        }
    }
    // epilogue (D: col=lane&15, row=(lane>>4)*4+reg)
    float bcol[4];
#pragma unroll
    for (int n = 0; n < 4; ++n) bcol[n] = bias[bn + wc * 64 + n * 16 + lr];
    float ssum[4] = {0.f, 0.f, 0.f, 0.f}, ssq[4] = {0.f, 0.f, 0.f, 0.f};
#pragma unroll
    for (int m = 0; m < 4; ++m) {
#pragma unroll
        for (int j = 0; j < 4; ++j) {
            const int grow = bm + wr * 64 + m * 16 + lg * 4 + j;
#pragma unroll
            for (int n = 0; n < 4; ++n) {
                const int gcol = bn + wc * 64 + n * 16 + lr;
                float v = acc[m][n][j] + bcol[n];
                if (RESID) v += b2f(resid[(size_t)grow * Nw + gcol]);
                if (RELU) v = fmaxf(v, 0.f);
                out[(size_t)grow * Nw + gcol] = f2b(v);
                if (STATS) { ssum[n] += v; ssq[n] += v * v; }
            }
        }
    }
    if (STATS) {
#pragma unroll
        for (int n = 0; n < 4; ++n) {
            ssum[n] += __shfl_xor(ssum[n], 16); ssum[n] += __shfl_xor(ssum[n], 32);
            ssq[n]  += __shfl_xor(ssq[n], 16);  ssq[n]  += __shfl_xor(ssq[n], 32);
        }
        if (lg == 0) {
#pragma unroll
            for (int n = 0; n < 4; ++n) {
                const int gcol = wc * 64 + n * 16 + lr;
                atomicAdd(&stats[gcol], ssum[n]);
                atomicAdd(&stats[128 + gcol], ssq[n]);
            }
        }
    }
}

// ================= MFMA attention, one block per (graph, head) =================
__global__ __launch_bounds__(256) void attn_mfma(const unsigned short* __restrict__ R,
                                                 unsigned short* __restrict__ O) {
    __shared__ __align__(16) unsigned short SH[128 * 128];  // Q[128][64]sw | K[128][64]sw -> P[128][128]sw
    __shared__ __align__(16) unsigned short Vp[128 * 72];   // V padded rows (144B)
    __shared__ float inv[128];
    const int b = blockIdx.x >> 1, h = blockIdx.x & 1;
    const int tid = threadIdx.x, lane = tid & 63, w = tid >> 6;
    const int lr = lane & 15, lg = lane >> 4;
    unsigned short* Qs = SH;
    unsigned short* Ks = SH + 128 * 64;
    const size_t rb = (size_t)b * 128 * 384 + h * 64;
#pragma unroll
    for (int i = 0; i < 4; ++i) {
        const int f = tid + i * 256;  // 0..1023
        const int r = f >> 3, ch = f & 7;
        *(uint4*)((char*)Qs + SWB(r, ch * 16, 128)) = *(const uint4*)(R + rb + (size_t)r * 384 + ch * 8);
        *(uint4*)((char*)Ks + SWB(r, ch * 16, 128)) = *(const uint4*)(R + rb + (size_t)r * 384 + 128 + ch * 8);
        *(uint4*)((char*)Vp + r * 144 + ch * 16) = *(const uint4*)(R + rb + (size_t)r * 384 + 256 + ch * 8);
    }
    __syncthreads();
    // S^T = K @ Q^T  (wave w: q in [w*32, w*32+32))
    f32x4 s[8][2];
#pragma unroll
    for (int m = 0; m < 8; ++m)
#pragma unroll
        for (int n = 0; n < 2; ++n) s[m][n] = (f32x4){0.f, 0.f, 0.f, 0.f};
#pragma unroll
    for (int kd = 0; kd < 2; ++kd) {
        bf16x8 ak[8], bq[2];
#pragma unroll
        for (int m = 0; m < 8; ++m)
            ak[m] = *(const bf16x8*)((const char*)Ks + SWB(m * 16 + lr, kd * 64 + lg * 16, 128));
#pragma unroll
        for (int n = 0; n < 2; ++n)
            bq[n] = *(const bf16x8*)((const char*)Qs + SWB(w * 32 + n * 16 + lr, kd * 64 + lg * 16, 128));
#pragma unroll
        for (int m = 0; m < 8; ++m)
#pragma unroll
            for (int n = 0; n < 2; ++n)
                s[m][n] = __builtin_amdgcn_mfma_f32_16x16x32_bf16(ak[m], bq[n], s[m][n], 0, 0, 0);
    }
    // in-register softmax over keys (column q = w*32 + n*16 + lr)
    const float SC = 0.125f * 1.44269504f;
#pragma unroll
    for (int n = 0; n < 2; ++n) {
        float mx = -1e30f;
#pragma unroll
        for (int m = 0; m < 8; ++m)
#pragma unroll
            for (int j = 0; j < 4; ++j) { s[m][n][j] *= SC; mx = fmaxf(mx, s[m][n][j]); }
        mx = fmaxf(mx, __shfl_xor(mx, 16));
        mx = fmaxf(mx, __shfl_xor(mx, 32));
        float sum = 0.f;
#pragma unroll
        for (int m = 0; m < 8; ++m)
#pragma unroll
            for (int j = 0; j < 4; ++j) {
                const float p = exp2f(s[m][n][j] - mx);
                s[m][n][j] = p;
                sum += p;
            }
        sum += __shfl_xor(sum, 16);
        sum += __shfl_xor(sum, 32);
        if (lg == 0) inv[w * 32 + n * 16 + lr] = 1.0f / sum;
    }
    __syncthreads();  // everyone done reading Q/K
    // write P[q][key] bf16 (swizzled 256B rows), 4 keys per b64
#pragma unroll
    for (int n = 0; n < 2; ++n) {
        const int q = w * 32 + n * 16 + lr;
#pragma unroll
        for (int m = 0; m < 8; ++m) {
            ushort4 pk;
            pk.x = f2b(s[m][n][0]); pk.y = f2b(s[m][n][1]);
            pk.z = f2b(s[m][n][2]); pk.w = f2b(s[m][n][3]);
            *(ushort4*)((char*)SH + SWB(q, (m * 16 + lg * 4) * 2, 256)) = pk;
        }
    }
    __syncthreads();
    // O = P @ V
    f32x4 o[2][4];
#pragma unroll
    for (int m = 0; m < 2; ++m)
#pragma unroll
        for (int n = 0; n < 4; ++n) o[m][n] = (f32x4){0.f, 0.f, 0.f, 0.f};
#pragma unroll
    for (int ks = 0; ks < 4; ++ks) {
        bf16x8 ap[2], bv[4];
#pragma unroll
        for (int m = 0; m < 2; ++m)
            ap[m] = *(const bf16x8*)((const char*)SH + SWB(w * 32 + m * 16 + lr, ks * 64 + lg * 16, 256));
#pragma unroll
        for (int n = 0; n < 4; ++n) {
            union { bf16x8 v; unsigned short u[8]; } t;
#pragma unroll
            for (int i = 0; i < 8; ++i) t.u[i] = Vp[(ks * 32 + lg * 8 + i) * 72 + n * 16 + lr];
            bv[n] = t.v;
        }
#pragma unroll
        for (int m = 0; m < 2; ++m)
#pragma unroll
            for (int n = 0; n < 4; ++n)
                o[m][n] = __builtin_amdgcn_mfma_f32_16x16x32_bf16(ap[m], bv[n], o[m][n], 0, 0, 0);
    }
#pragma unroll
    for (int m = 0; m < 2; ++m)
#pragma unroll
        for (int j = 0; j < 4; ++j) {
            const int q = w * 32 + m * 16 + lg * 4 + j;
            const float sc = inv[q];
            const size_t node = (size_t)b * 128 + q;
#pragma unroll
            for (int n = 0; n < 4; ++n)
                O[node * 128 + h * 64 + n * 16 + lr] = f2b(o[m][n][j] * sc);
        }
}

extern "C" void kernel_launch(void* const* d_in, const int* in_sizes, int n_in,
                              void* d_out, int out_size, void* d_ws, size_t ws_size,
                              hipStream_t stream) {
    const int* node_type = (const int*)d_in[0];
    const float* pe = (const float*)d_in[1];
    const int* eidx = (const int*)d_in[2];
    const int* etype = (const int*)d_in[3];
    const float* pe_gamma = (const float*)d_in[5];
    const float* pe_beta = (const float*)d_in[6];
    const float* pe_W = (const float*)d_in[7];
    const float* pe_b = (const float*)d_in[8];
    const float* node_emb = (const float*)d_in[9];
    const float* edge_emb = (const float*)d_in[10];
    const float* gine_W1 = (const float*)d_in[11];
    const float* gine_b1 = (const float*)d_in[12];
    const float* gine_W2 = (const float*)d_in[13];
    const float* gine_b2 = (const float*)d_in[14];
    const float* n1_g = (const float*)d_in[15];
    const float* n1_b = (const float*)d_in[16];
    const float* n2_g = (const float*)d_in[17];
    const float* n2_b = (const float*)d_in[18];
    const float* n3_g = (const float*)d_in[19];
    const float* n3_b = (const float*)d_in[20];
    const float* attn_inW = (const float*)d_in[21];
    const float* attn_inb = (const float*)d_in[22];
    const float* attn_outW = (const float*)d_in[23];
    const float* attn_outb = (const float*)d_in[24];
    const float* mlp_W1 = (const float*)d_in[25];
    const float* mlp_b1 = (const float*)d_in[26];
    const float* mlp_W2 = (const float*)d_in[27];
    const float* mlp_b2 = (const float*)d_in[28];

    const size_t NC = (size_t)NN * CC;
    unsigned short* XB = (unsigned short*)d_ws;      // [N,128] bf16 backbone
    unsigned short* Zb = XB + NC;                    // [N,128]
    unsigned short* T1 = Zb + NC;                    // [N,128] t1 / attn-o
    unsigned short* HA = T1 + NC;                    // [N,128]
    unsigned short* OUTb = HA + NC;                  // [N,128]
    unsigned short* Rq = OUTb + NC;                  // [N,384] qkv
    unsigned short* T2 = Rq + 3 * NC;                // [N,256]
    unsigned short* WB = T2 + 2 * NC;                // 491520 bf16 weights
    float* STATS = (float*)(WB + 491520);            // 768
    float* SCOFF = STATS + 768;                      // 512 (layer) + 64 (pe)
    float* SCPE = SCOFF + 512;
    int* icnt = (int*)(SCPE + 64);
    int* irow = icnt + NN;
    int* ielist = irow + NN + 1;
    int* ipart = ielist + EE;

    const int EW16 = NN * 16 / 256;  // grids for 8-elem/thread elementwise (=4096)
    const float invn = 1.f / (float)NN;
    float* outF = (float*)d_out;

    // ---- CSR build ----
    hipMemsetAsync(icnt, 0, NN * sizeof(int), stream);
    hist_k<<<EE / 256, 256, 0, stream>>>(eidx, icnt);
    scan1_k<<<NN / 256, 256, 0, stream>>>(icnt, irow, ipart);
    scan2_k<<<1, 256, 0, stream>>>(ipart);
    scan3_k<<<NN / 256, 256, 0, stream>>>(irow, ipart);
    hipMemsetAsync(icnt, 0, NN * sizeof(int), stream);
    fill_k<<<EE / 256, 256, 0, stream>>>(eidx, irow, icnt, ielist);

    // ---- weights -> bf16 WT ----
    cvtw<<<491520 / 256, 256, 0, stream>>>(gine_W1, gine_W2, attn_inW, attn_outW, mlp_W1, mlp_W2, WB);

    // ---- input featurization ----
    colstats_pe<<<20, 256, 0, stream>>>(pe, STATS);
    bn_finalize<<<1, 64, 0, stream>>>(STATS, pe_gamma, pe_beta, SCPE, 20, invn);
    embed_b<<<EW16, 256, 0, stream>>>(node_type, pe, SCPE, pe_W, pe_b, node_emb, XB);

    const dim3 g1(NN / 128, 1), g2(NN / 128, 2), g3(NN / 128, 3);
    for (int l = 0; l < LL; ++l) {
        unsigned short* WL = WB + (size_t)l * 163840;
        unsigned short* gW1T = WL;
        unsigned short* gW2T = WL + 16384;
        unsigned short* inWT = WL + 32768;
        unsigned short* oWT = WL + 81920;
        unsigned short* mW1T = WL + 98304;
        unsigned short* mW2T = WL + 131072;
        const float* gb1 = gine_b1 + (size_t)l * CC;
        const float* gb2 = gine_b2 + (size_t)l * CC;
        const float* inb = attn_inb + (size_t)l * 384;
        const float* ob = attn_outb + (size_t)l * CC;
        const float* mb1 = mlp_b1 + (size_t)l * 256;
        const float* mb2 = mlp_b2 + (size_t)l * CC;

        hipMemsetAsync(STATS, 0, 768 * sizeof(float), stream);

        // ---- GINEConv ----
        gine_gather_b<<<NN / 16, 256, 0, stream>>>(XB, eidx, etype, edge_emb, irow, ielist, Zb);
        gemm_bf<1, 0, 0, 1><<<g1, 256, 0, stream>>>(Zb, gW1T, gb1, nullptr, T1, nullptr, 128);
        gemm_bf<0, 1, 1, 1><<<g1, 256, 0, stream>>>(T1, gW2T, gb2, XB, Zb, STATS, 128);
        bn_finalize<<<1, 128, 0, stream>>>(STATS, n1_g + l * CC, n1_b + l * CC, SCOFF, 128, invn);

        // ---- attention ----
        gemm_bf<0, 0, 0, 1><<<g3, 256, 0, stream>>>(XB, inWT, inb, nullptr, Rq, nullptr, 384);
        attn_mfma<<<BB * 2, 256, 0, stream>>>(Rq, T1);
        gemm_bf<0, 1, 1, 1><<<g1, 256, 0, stream>>>(T1, oWT, ob, XB, HA, STATS + 256, 128);
        bn_finalize<<<1, 128, 0, stream>>>(STATS + 256, n2_g + l * CC, n2_b + l * CC, SCOFF + 256, 128, invn);

        // ---- combine + FFN ----
        combine2<<<EW16, 256, 0, stream>>>(Zb, HA, SCOFF, OUTb);
        gemm_bf<1, 0, 0, 1><<<g2, 256, 0, stream>>>(OUTb, mW1T, mb1, nullptr, T2, nullptr, 256);
        gemm_bf<0, 1, 1, 2><<<g1, 256, 0, stream>>>(T2, mW2T, mb2, OUTb, Zb, STATS + 512, 128);
        bn_finalize<<<1, 128, 0, stream>>>(STATS + 512, n3_g + l * CC, n3_b + l * CC, SCOFF, 128, invn);
        if (l < LL - 1)
            bn_apply_b<<<EW16, 256, 0, stream>>>(Zb, SCOFF, XB);
        else
            bn_apply_f<<<EW16, 256, 0, stream>>>(Zb, SCOFF, outF);
    }
}

// Round 4
// 846.072 us; speedup vs baseline: 4.9030x; 1.0456x over previous
//
#include <hip/hip_runtime.h>
#include <hip/hip_bf16.h>

#define NN 65536
#define SS 128
#define CC 128
#define EE 262144
#define BB 512
#define LL 3

typedef __attribute__((ext_vector_type(8))) short bf16x8;
typedef __attribute__((ext_vector_type(4))) float f32x4;

__device__ __forceinline__ float b2f(unsigned short u) {
    union { unsigned int i; float f; } x; x.i = ((unsigned int)u) << 16; return x.f;
}
__device__ __forceinline__ unsigned short f2b(float f) {
    union { float f; unsigned int i; } x; x.f = f;
    unsigned int r = x.i + 0x7fffu + ((x.i >> 16) & 1u);
    return (unsigned short)(r >> 16);
}
// swizzled byte offset within a tile of row-stride ROWB bytes
#define SWB(row, colbyte, ROWB) ((row) * (ROWB) + ((colbyte) ^ (((row) & 7) << 4)))

// ================= CSR build =================
__global__ __launch_bounds__(256) void hist_k(const int* __restrict__ eidx, int* __restrict__ cnt) {
    const int e = blockIdx.x * 256 + threadIdx.x;
    atomicAdd(&cnt[eidx[EE + e]], 1);
}
__global__ __launch_bounds__(256) void scan1_k(const int* __restrict__ cnt, int* __restrict__ row,
                                               int* __restrict__ part) {
    __shared__ int s[256];
    const int tid = threadIdx.x;
    const int i = blockIdx.x * 256 + tid;
    const int v = cnt[i];
    s[tid] = v;
    __syncthreads();
    for (int off = 1; off < 256; off <<= 1) {
        int t = (tid >= off) ? s[tid - off] : 0;
        __syncthreads(); s[tid] += t; __syncthreads();
    }
    row[i] = s[tid] - v;
    if (tid == 255) part[blockIdx.x] = s[255];
}
__global__ __launch_bounds__(256) void scan2_k(int* __restrict__ part) {
    __shared__ int s[256];
    const int tid = threadIdx.x;
    const int v = part[tid];
    s[tid] = v;
    __syncthreads();
    for (int off = 1; off < 256; off <<= 1) {
        int t = (tid >= off) ? s[tid - off] : 0;
        __syncthreads(); s[tid] += t; __syncthreads();
    }
    part[tid] = s[tid] - v;
}
__global__ __launch_bounds__(256) void scan3_k(int* __restrict__ row, const int* __restrict__ part) {
    const int i = blockIdx.x * 256 + threadIdx.x;
    row[i] += part[blockIdx.x];
    if (i == 0) row[NN] = EE;
}
__global__ __launch_bounds__(256) void fill_k(const int* __restrict__ eidx, const int* __restrict__ row,
                                              int* __restrict__ cnt, int* __restrict__ elist) {
    const int e = blockIdx.x * 256 + threadIdx.x;
    const int d = eidx[EE + e];
    const int slot = row[d] + atomicAdd(&cnt[d], 1);
    elist[slot] = e;
}

// ================= weight convert + transpose to bf16 WT[N][K] =================
__global__ __launch_bounds__(256) void cvtw(const float* __restrict__ gW1, const float* __restrict__ gW2,
                                            const float* __restrict__ inW, const float* __restrict__ oW,
                                            const float* __restrict__ mW1, const float* __restrict__ mW2,
                                            unsigned short* __restrict__ WB) {
    const int g = blockIdx.x * 256 + threadIdx.x;  // 0 .. 3*163840
    const int l = g / 163840;
    const int r = g % 163840;
    const float* src; int K, Nc, dst, i;
    if (r < 16384)       { src = gW1 + l * 16384; K = 128; Nc = 128; dst = 0;      i = r; }
    else if (r < 32768)  { src = gW2 + l * 16384; K = 128; Nc = 128; dst = 16384;  i = r - 16384; }
    else if (r < 81920)  { src = inW + l * 49152; K = 128; Nc = 384; dst = 32768;  i = r - 32768; }
    else if (r < 98304)  { src = oW  + l * 16384; K = 128; Nc = 128; dst = 81920;  i = r - 81920; }
    else if (r < 131072) { src = mW1 + l * 32768; K = 128; Nc = 256; dst = 98304;  i = r - 98304; }
    else                 { src = mW2 + l * 32768; K = 256; Nc = 128; dst = 131072; i = r - 131072; }
    const int k = i / Nc, c = i % Nc;
    WB[(size_t)l * 163840 + dst + (size_t)c * K + k] = f2b(src[i]);
}

// ================= pe column stats: one row per thread, 256 blocks =================
__global__ __launch_bounds__(256) void colstats_pe(const float* __restrict__ pe,
                                                   float* __restrict__ stats) {
    const int r = blockIdx.x * 256 + threadIdx.x;
    const float* p = pe + (size_t)r * 20;
    float v[20];
    *(float4*)&v[0]  = *(const float4*)(p);
    *(float4*)&v[4]  = *(const float4*)(p + 4);
    *(float4*)&v[8]  = *(const float4*)(p + 8);
    *(float4*)&v[12] = *(const float4*)(p + 12);
    *(float4*)&v[16] = *(const float4*)(p + 16);
    float s[20], q[20];
#pragma unroll
    for (int i = 0; i < 20; ++i) { s[i] = v[i]; q[i] = v[i] * v[i]; }
#pragma unroll
    for (int off = 1; off < 64; off <<= 1) {
#pragma unroll
        for (int i = 0; i < 20; ++i) {
            s[i] += __shfl_xor(s[i], off);
            q[i] += __shfl_xor(q[i], off);
        }
    }
    __shared__ float red[4][40];
    const int lane = threadIdx.x & 63, w = threadIdx.x >> 6;
    if (lane == 0) {
#pragma unroll
        for (int i = 0; i < 20; ++i) { red[w][i] = s[i]; red[w][20 + i] = q[i]; }
    }
    __syncthreads();
    if (threadIdx.x < 40) {
        const float t = red[0][threadIdx.x] + red[1][threadIdx.x] +
                        red[2][threadIdx.x] + red[3][threadIdx.x];
        atomicAdd(&stats[threadIdx.x], t);
    }
}

// ================= BN helpers =================
__global__ void bn_finalize(const float* __restrict__ stats, const float* __restrict__ g,
                            const float* __restrict__ b, float* __restrict__ scoff,
                            int ncols, float invn) {
    const int c = threadIdx.x;
    if (c < ncols) {
        float m = stats[c] * invn;
        float var = stats[ncols + c] * invn - m * m;
        float rs = rsqrtf(var + 1e-5f);
        float sc = g[c] * rs;
        scoff[c] = sc;
        scoff[ncols + c] = b[c] - m * sc;
    }
}
// XB (bf16) <- bn(Z f32)
__global__ __launch_bounds__(256) void bn_apply_b(const float* __restrict__ in,
                                                  const float* __restrict__ scoff,
                                                  unsigned short* __restrict__ out) {
    const size_t g = (size_t)blockIdx.x * 256 + threadIdx.x;  // N*16
    const int c8 = ((int)g & 15) << 3;
    float4 a0 = *(const float4*)(in + g * 8);
    float4 a1 = *(const float4*)(in + g * 8 + 4);
    float v[8] = {a0.x, a0.y, a0.z, a0.w, a1.x, a1.y, a1.z, a1.w};
    union { uint4 u; unsigned short s[8]; } o;
#pragma unroll
    for (int i = 0; i < 8; ++i) o.s[i] = f2b(v[i] * scoff[c8 + i] + scoff[128 + c8 + i]);
    *(uint4*)(out + g * 8) = o.u;
}
// d_out (f32) <- bn(Z f32)
__global__ __launch_bounds__(256) void bn_apply_f(const float* __restrict__ in,
                                                  const float* __restrict__ scoff,
                                                  float* __restrict__ out) {
    const size_t g = (size_t)blockIdx.x * 256 + threadIdx.x;
    const int c8 = ((int)g & 15) << 3;
    float4 a0 = *(const float4*)(in + g * 8);
    float4 a1 = *(const float4*)(in + g * 8 + 4);
    float v[8] = {a0.x, a0.y, a0.z, a0.w, a1.x, a1.y, a1.z, a1.w};
    float4 o0, o1;
    o0.x = v[0] * scoff[c8 + 0] + scoff[128 + c8 + 0];
    o0.y = v[1] * scoff[c8 + 1] + scoff[128 + c8 + 1];
    o0.z = v[2] * scoff[c8 + 2] + scoff[128 + c8 + 2];
    o0.w = v[3] * scoff[c8 + 3] + scoff[128 + c8 + 3];
    o1.x = v[4] * scoff[c8 + 4] + scoff[128 + c8 + 4];
    o1.y = v[5] * scoff[c8 + 5] + scoff[128 + c8 + 5];
    o1.z = v[6] * scoff[c8 + 6] + scoff[128 + c8 + 6];
    o1.w = v[7] * scoff[c8 + 7] + scoff[128 + c8 + 7];
    *(float4*)(out + g * 8) = o0;
    *(float4*)(out + g * 8 + 4) = o1;
}
// OUT(bf16) = bn1(Z f32) + bn2(HA f32)
__global__ __launch_bounds__(256) void combine2(const float* __restrict__ z,
                                                const float* __restrict__ ha,
                                                const float* __restrict__ scoff,
                                                unsigned short* __restrict__ out) {
    const size_t g = (size_t)blockIdx.x * 256 + threadIdx.x;
    const int c8 = ((int)g & 15) << 3;
    float4 a0 = *(const float4*)(z + g * 8);
    float4 a1 = *(const float4*)(z + g * 8 + 4);
    float4 b0 = *(const float4*)(ha + g * 8);
    float4 b1 = *(const float4*)(ha + g * 8 + 4);
    float va[8] = {a0.x, a0.y, a0.z, a0.w, a1.x, a1.y, a1.z, a1.w};
    float vb[8] = {b0.x, b0.y, b0.z, b0.w, b1.x, b1.y, b1.z, b1.w};
    union { uint4 u; unsigned short s[8]; } o;
#pragma unroll
    for (int i = 0; i < 8; ++i) {
        const int c = c8 + i;
        o.s[i] = f2b(va[i] * scoff[c] + scoff[128 + c] +
                     vb[i] * scoff[256 + c] + scoff[384 + c]);
    }
    *(uint4*)(out + g * 8) = o.u;
}

// ================= input featurization -> XB bf16 =================
__global__ __launch_bounds__(256) void embed_b(const int* __restrict__ node_type,
                                               const float* __restrict__ pe,
                                               const float* __restrict__ scoff,
                                               const float* __restrict__ peW,
                                               const float* __restrict__ peB,
                                               const float* __restrict__ node_emb,
                                               unsigned short* __restrict__ XB) {
    const int g = blockIdx.x * 256 + threadIdx.x;  // N*16
    const int n = g >> 4, c8 = (g & 15) << 3;
    float v[8];
    if (c8 < 120) {
        const float4 a = *(const float4*)(node_emb + (size_t)node_type[n] * 120 + c8);
        const float4 b = *(const float4*)(node_emb + (size_t)node_type[n] * 120 + c8 + 4);
        v[0] = a.x; v[1] = a.y; v[2] = a.z; v[3] = a.w;
        v[4] = b.x; v[5] = b.y; v[6] = b.z; v[7] = b.w;
    } else {
#pragma unroll
        for (int j = 0; j < 8; ++j) v[j] = peB[j];
#pragma unroll
        for (int k = 0; k < 20; ++k) {
            const float p = pe[(size_t)n * 20 + k] * scoff[k] + scoff[20 + k];
#pragma unroll
            for (int j = 0; j < 8; ++j) v[j] = fmaf(p, peW[k * 8 + j], v[j]);
        }
    }
    union { uint4 u; unsigned short s[8]; } o;
#pragma unroll
    for (int i = 0; i < 8; ++i) o.s[i] = f2b(v[i]);
    *(uint4*)(XB + (size_t)g * 8) = o.u;
}

// ================= GINE gather: Z = X + sum relu(X[src]+ee)  (bf16) =================
__global__ __launch_bounds__(256) void gine_gather_b(const unsigned short* __restrict__ XB,
                                                     const int* __restrict__ eidx,
                                                     const int* __restrict__ etype,
                                                     const float* __restrict__ edge_emb,
                                                     const int* __restrict__ row,
                                                     const int* __restrict__ elist,
                                                     unsigned short* __restrict__ Z) {
    const int n = blockIdx.x * 16 + (threadIdx.x >> 4);
    const int c8 = (threadIdx.x & 15) << 3;
    const int beg = row[n], end = row[n + 1];
    union { uint4 u; unsigned short s[8]; } x;
    x.u = *(const uint4*)(XB + (size_t)n * 128 + c8);
    float z[8];
#pragma unroll
    for (int i = 0; i < 8; ++i) z[i] = b2f(x.s[i]);
    for (int j = beg; j < end; ++j) {
        const int e = elist[j];
        const int s = eidx[e];
        const int et = etype[e];
        union { uint4 u; unsigned short s[8]; } xs;
        xs.u = *(const uint4*)(XB + (size_t)s * 128 + c8);
        const float4 e0 = *(const float4*)(edge_emb + (size_t)et * 128 + c8);
        const float4 e1 = *(const float4*)(edge_emb + (size_t)et * 128 + c8 + 4);
        z[0] += fmaxf(b2f(xs.s[0]) + e0.x, 0.f);
        z[1] += fmaxf(b2f(xs.s[1]) + e0.y, 0.f);
        z[2] += fmaxf(b2f(xs.s[2]) + e0.z, 0.f);
        z[3] += fmaxf(b2f(xs.s[3]) + e0.w, 0.f);
        z[4] += fmaxf(b2f(xs.s[4]) + e1.x, 0.f);
        z[5] += fmaxf(b2f(xs.s[5]) + e1.y, 0.f);
        z[6] += fmaxf(b2f(xs.s[6]) + e1.z, 0.f);
        z[7] += fmaxf(b2f(xs.s[7]) + e1.w, 0.f);
    }
    union { uint4 u; unsigned short s[8]; } o;
#pragma unroll
    for (int i = 0; i < 8; ++i) o.s[i] = f2b(z[i]);
    *(uint4*)(Z + (size_t)n * 128 + c8) = o.u;
}

// ================= MFMA bf16 GEMM: out[M,Nw] = act(A[M,K] @ WT[Nw,K]^T + bias [+resid]) =================
// 128x128 tile, 4 waves (2x2), 16x16x32 MFMA, XOR-swizzled LDS. OUTF: fp32 output.
template <int RELU, int RESID, int STATS, int KT, int OUTF>
__global__ __launch_bounds__(256) void gemm_bf(const unsigned short* __restrict__ A,
                                               const unsigned short* __restrict__ WT,
                                               const float* __restrict__ bias,
                                               const unsigned short* __restrict__ resid,
                                               void* __restrict__ outp,
                                               float* __restrict__ stats, int Nw) {
    __shared__ __align__(16) unsigned short As[128 * 128];
    __shared__ __align__(16) unsigned short Bs[128 * 128];
    const int bm = blockIdx.x * 128, bn = blockIdx.y * 128;
    const int tid = threadIdx.x;
    const int lane = tid & 63, w = tid >> 6, wr = w >> 1, wc = w & 1;
    const int lr = lane & 15, lg = lane >> 4;
    const int K = KT * 128;
    f32x4 acc[4][4];
#pragma unroll
    for (int m = 0; m < 4; ++m)
#pragma unroll
        for (int n = 0; n < 4; ++n) acc[m][n] = (f32x4){0.f, 0.f, 0.f, 0.f};

    for (int kt = 0; kt < KT; ++kt) {
        if (kt) __syncthreads();
#pragma unroll
        for (int i = 0; i < 8; ++i) {
            const int f = tid + i * 256;
            const int r = f >> 4, ch = f & 15;
            *(uint4*)((char*)As + SWB(r, ch * 16, 256)) =
                *(const uint4*)(A + (size_t)(bm + r) * K + kt * 128 + ch * 8);
            *(uint4*)((char*)Bs + SWB(r, ch * 16, 256)) =
                *(const uint4*)(WT + (size_t)(bn + r) * K + kt * 128 + ch * 8);
        }
        __syncthreads();
#pragma unroll
        for (int ks = 0; ks < 4; ++ks) {
            bf16x8 af[4], bfr[4];
#pragma unroll
            for (int m = 0; m < 4; ++m) {
                const int row = wr * 64 + m * 16 + lr;
                af[m] = *(const bf16x8*)((const char*)As + SWB(row, ks * 64 + lg * 16, 256));
            }
#pragma unroll
            for (int n = 0; n < 4; ++n) {
                const int row = wc * 64 + n * 16 + lr;
                bfr[n] = *(const bf16x8*)((const char*)Bs + SWB(row, ks * 64 + lg * 16, 256));
            }
#pragma unroll
            for (int m = 0; m < 4; ++m)
#pragma unroll
                for (int n = 0; n < 4; ++n)
                    acc[m][n] = __builtin_amdgcn_mfma_f32_16x16x32_bf16(af[m], bfr[n], acc[m][n], 0, 0, 0);
        }
    }
    // epilogue (D: col=lane&15, row=(lane>>4)*4+reg)
    float bcol[4];
#pragma unroll
    for (int n = 0; n < 4; ++n) bcol[n] = bias[bn + wc * 64 + n * 16 + lr];
    float ssum[4] = {0.f, 0.f, 0.f, 0.f}, ssq[4] = {0.f, 0.f, 0.f, 0.f};
#pragma unroll
    for (int m = 0; m < 4; ++m) {
#pragma unroll
        for (int j = 0; j < 4; ++j) {
            const int grow = bm + wr * 64 + m * 16 + lg * 4 + j;
#pragma unroll
            for (int n = 0; n < 4; ++n) {
                const int gcol = bn + wc * 64 + n * 16 + lr;
                float v = acc[m][n][j] + bcol[n];
                if (RESID) v += b2f(resid[(size_t)grow * Nw + gcol]);
                if (RELU) v = fmaxf(v, 0.f);
                if (OUTF) ((float*)outp)[(size_t)grow * Nw + gcol] = v;
                else ((unsigned short*)outp)[(size_t)grow * Nw + gcol] = f2b(v);
                if (STATS) { ssum[n] += v; ssq[n] += v * v; }
            }
        }
    }
    if (STATS) {
#pragma unroll
        for (int n = 0; n < 4; ++n) {
            ssum[n] += __shfl_xor(ssum[n], 16); ssum[n] += __shfl_xor(ssum[n], 32);
            ssq[n]  += __shfl_xor(ssq[n], 16);  ssq[n]  += __shfl_xor(ssq[n], 32);
        }
        if (lg == 0) {
#pragma unroll
            for (int n = 0; n < 4; ++n) {
                const int gcol = wc * 64 + n * 16 + lr;
                atomicAdd(&stats[gcol], ssum[n]);
                atomicAdd(&stats[128 + gcol], ssq[n]);
            }
        }
    }
}

// ================= MFMA attention, one block per (graph, head) =================
__global__ __launch_bounds__(256) void attn_mfma(const unsigned short* __restrict__ R,
                                                 unsigned short* __restrict__ O) {
    __shared__ __align__(16) unsigned short SH[128 * 128];  // Q[128][64]sw | K[128][64]sw -> P[128][128]sw
    __shared__ __align__(16) unsigned short Vp[128 * 72];   // V padded rows (144B)
    __shared__ float inv[128];
    const int b = blockIdx.x >> 1, h = blockIdx.x & 1;
    const int tid = threadIdx.x, lane = tid & 63, w = tid >> 6;
    const int lr = lane & 15, lg = lane >> 4;
    unsigned short* Qs = SH;
    unsigned short* Ks = SH + 128 * 64;
    const size_t rb = (size_t)b * 128 * 384 + h * 64;
#pragma unroll
    for (int i = 0; i < 4; ++i) {
        const int f = tid + i * 256;  // 0..1023
        const int r = f >> 3, ch = f & 7;
        *(uint4*)((char*)Qs + SWB(r, ch * 16, 128)) = *(const uint4*)(R + rb + (size_t)r * 384 + ch * 8);
        *(uint4*)((char*)Ks + SWB(r, ch * 16, 128)) = *(const uint4*)(R + rb + (size_t)r * 384 + 128 + ch * 8);
        *(uint4*)((char*)Vp + r * 144 + ch * 16) = *(const uint4*)(R + rb + (size_t)r * 384 + 256 + ch * 8);
    }
    __syncthreads();
    // S^T = K @ Q^T  (wave w: q in [w*32, w*32+32))
    f32x4 s[8][2];
#pragma unroll
    for (int m = 0; m < 8; ++m)
#pragma unroll
        for (int n = 0; n < 2; ++n) s[m][n] = (f32x4){0.f, 0.f, 0.f, 0.f};
#pragma unroll
    for (int kd = 0; kd < 2; ++kd) {
        bf16x8 ak[8], bq[2];
#pragma unroll
        for (int m = 0; m < 8; ++m)
            ak[m] = *(const bf16x8*)((const char*)Ks + SWB(m * 16 + lr, kd * 64 + lg * 16, 128));
#pragma unroll
        for (int n = 0; n < 2; ++n)
            bq[n] = *(const bf16x8*)((const char*)Qs + SWB(w * 32 + n * 16 + lr, kd * 64 + lg * 16, 128));
#pragma unroll
        for (int m = 0; m < 8; ++m)
#pragma unroll
            for (int n = 0; n < 2; ++n)
                s[m][n] = __builtin_amdgcn_mfma_f32_16x16x32_bf16(ak[m], bq[n], s[m][n], 0, 0, 0);
    }
    // in-register softmax over keys (column q = w*32 + n*16 + lr)
    const float SC = 0.125f * 1.44269504f;
#pragma unroll
    for (int n = 0; n < 2; ++n) {
        float mx = -1e30f;
#pragma unroll
        for (int m = 0; m < 8; ++m)
#pragma unroll
            for (int j = 0; j < 4; ++j) { s[m][n][j] *= SC; mx = fmaxf(mx, s[m][n][j]); }
        mx = fmaxf(mx, __shfl_xor(mx, 16));
        mx = fmaxf(mx, __shfl_xor(mx, 32));
        float sum = 0.f;
#pragma unroll
        for (int m = 0; m < 8; ++m)
#pragma unroll
            for (int j = 0; j < 4; ++j) {
                const float p = exp2f(s[m][n][j] - mx);
                s[m][n][j] = p;
                sum += p;
            }
        sum += __shfl_xor(sum, 16);
        sum += __shfl_xor(sum, 32);
        if (lg == 0) inv[w * 32 + n * 16 + lr] = 1.0f / sum;
    }
    __syncthreads();  // everyone done reading Q/K
    // write P[q][key] bf16 (swizzled 256B rows), 4 keys per b64
#pragma unroll
    for (int n = 0; n < 2; ++n) {
        const int q = w * 32 + n * 16 + lr;
#pragma unroll
        for (int m = 0; m < 8; ++m) {
            ushort4 pk;
            pk.x = f2b(s[m][n][0]); pk.y = f2b(s[m][n][1]);
            pk.z = f2b(s[m][n][2]); pk.w = f2b(s[m][n][3]);
            *(ushort4*)((char*)SH + SWB(q, (m * 16 + lg * 4) * 2, 256)) = pk;
        }
    }
    __syncthreads();
    // O = P @ V
    f32x4 o[2][4];
#pragma unroll
    for (int m = 0; m < 2; ++m)
#pragma unroll
        for (int n = 0; n < 4; ++n) o[m][n] = (f32x4){0.f, 0.f, 0.f, 0.f};
#pragma unroll
    for (int ks = 0; ks < 4; ++ks) {
        bf16x8 ap[2], bv[4];
#pragma unroll
        for (int m = 0; m < 2; ++m)
            ap[m] = *(const bf16x8*)((const char*)SH + SWB(w * 32 + m * 16 + lr, ks * 64 + lg * 16, 256));
#pragma unroll
        for (int n = 0; n < 4; ++n) {
            union { bf16x8 v; unsigned short u[8]; } t;
#pragma unroll
            for (int i = 0; i < 8; ++i) t.u[i] = Vp[(ks * 32 + lg * 8 + i) * 72 + n * 16 + lr];
            bv[n] = t.v;
        }
#pragma unroll
        for (int m = 0; m < 2; ++m)
#pragma unroll
            for (int n = 0; n < 4; ++n)
                o[m][n] = __builtin_amdgcn_mfma_f32_16x16x32_bf16(ap[m], bv[n], o[m][n], 0, 0, 0);
    }
#pragma unroll
    for (int m = 0; m < 2; ++m)
#pragma unroll
        for (int j = 0; j < 4; ++j) {
            const int q = w * 32 + m * 16 + lg * 4 + j;
            const float sc = inv[q];
            const size_t node = (size_t)b * 128 + q;
#pragma unroll
            for (int n = 0; n < 4; ++n)
                O[node * 128 + h * 64 + n * 16 + lr] = f2b(o[m][n][j] * sc);
        }
}

extern "C" void kernel_launch(void* const* d_in, const int* in_sizes, int n_in,
                              void* d_out, int out_size, void* d_ws, size_t ws_size,
                              hipStream_t stream) {
    const int* node_type = (const int*)d_in[0];
    const float* pe = (const float*)d_in[1];
    const int* eidx = (const int*)d_in[2];
    const int* etype = (const int*)d_in[3];
    const float* pe_gamma = (const float*)d_in[5];
    const float* pe_beta = (const float*)d_in[6];
    const float* pe_W = (const float*)d_in[7];
    const float* pe_b = (const float*)d_in[8];
    const float* node_emb = (const float*)d_in[9];
    const float* edge_emb = (const float*)d_in[10];
    const float* gine_W1 = (const float*)d_in[11];
    const float* gine_b1 = (const float*)d_in[12];
    const float* gine_W2 = (const float*)d_in[13];
    const float* gine_b2 = (const float*)d_in[14];
    const float* n1_g = (const float*)d_in[15];
    const float* n1_b = (const float*)d_in[16];
    const float* n2_g = (const float*)d_in[17];
    const float* n2_b = (const float*)d_in[18];
    const float* n3_g = (const float*)d_in[19];
    const float* n3_b = (const float*)d_in[20];
    const float* attn_inW = (const float*)d_in[21];
    const float* attn_inb = (const float*)d_in[22];
    const float* attn_outW = (const float*)d_in[23];
    const float* attn_outb = (const float*)d_in[24];
    const float* mlp_W1 = (const float*)d_in[25];
    const float* mlp_b1 = (const float*)d_in[26];
    const float* mlp_W2 = (const float*)d_in[27];
    const float* mlp_b2 = (const float*)d_in[28];

    const size_t NC = (size_t)NN * CC;
    // bf16 buffers
    unsigned short* XB = (unsigned short*)d_ws;      // [N,128] bf16 backbone
    unsigned short* Zb = XB + NC;                    // [N,128] gather out
    unsigned short* T1 = Zb + NC;                    // [N,128] t1 / attn-o
    unsigned short* Rq = T1 + NC;                    // [N,384] qkv
    // aliases inside Rq (qkv dead before these are written; they die before next qkv)
    float* HAf = (float*)Rq;                         // [N,128] f32 ha_pre
    unsigned short* OUTb = Rq + 2 * NC;              // [N,128] bf16 combined out
    unsigned short* T2 = Rq + 3 * NC;                // [N,256] bf16
    float* Zf = (float*)(T2 + 2 * NC);               // [N,128] f32 h_pre / out2
    unsigned short* WB = (unsigned short*)(Zf + NC); // 491520 bf16 weights
    float* STATS = (float*)(WB + 491520);            // 768
    float* SCOFF = STATS + 768;                      // 512 (layer)
    float* SCPE = SCOFF + 512;                       // 64 (pe)
    int* icnt = (int*)(SCPE + 64);
    int* irow = icnt + NN;
    int* ielist = irow + NN + 1;
    int* ipart = ielist + EE;

    const int EW16 = NN * 16 / 256;  // grids for 8-elem/thread elementwise (=4096)
    const float invn = 1.f / (float)NN;
    float* outF = (float*)d_out;

    // ---- CSR build ----
    hipMemsetAsync(icnt, 0, NN * sizeof(int), stream);
    hist_k<<<EE / 256, 256, 0, stream>>>(eidx, icnt);
    scan1_k<<<NN / 256, 256, 0, stream>>>(icnt, irow, ipart);
    scan2_k<<<1, 256, 0, stream>>>(ipart);
    scan3_k<<<NN / 256, 256, 0, stream>>>(irow, ipart);
    hipMemsetAsync(icnt, 0, NN * sizeof(int), stream);
    fill_k<<<EE / 256, 256, 0, stream>>>(eidx, irow, icnt, ielist);

    // ---- weights -> bf16 WT ----
    cvtw<<<491520 / 256, 256, 0, stream>>>(gine_W1, gine_W2, attn_inW, attn_outW, mlp_W1, mlp_W2, WB);

    // ---- input featurization ----
    hipMemsetAsync(STATS, 0, 64 * sizeof(float), stream);
    colstats_pe<<<NN / 256, 256, 0, stream>>>(pe, STATS);
    bn_finalize<<<1, 64, 0, stream>>>(STATS, pe_gamma, pe_beta, SCPE, 20, invn);
    embed_b<<<EW16, 256, 0, stream>>>(node_type, pe, SCPE, pe_W, pe_b, node_emb, XB);

    const dim3 g1(NN / 128, 1), g2(NN / 128, 2), g3(NN / 128, 3);
    for (int l = 0; l < LL; ++l) {
        unsigned short* WL = WB + (size_t)l * 163840;
        unsigned short* gW1T = WL;
        unsigned short* gW2T = WL + 16384;
        unsigned short* inWT = WL + 32768;
        unsigned short* oWT = WL + 81920;
        unsigned short* mW1T = WL + 98304;
        unsigned short* mW2T = WL + 131072;
        const float* gb1 = gine_b1 + (size_t)l * CC;
        const float* gb2 = gine_b2 + (size_t)l * CC;
        const float* inb = attn_inb + (size_t)l * 384;
        const float* ob = attn_outb + (size_t)l * CC;
        const float* mb1 = mlp_b1 + (size_t)l * 256;
        const float* mb2 = mlp_b2 + (size_t)l * CC;

        hipMemsetAsync(STATS, 0, 768 * sizeof(float), stream);

        // ---- GINEConv ----
        gine_gather_b<<<NN / 16, 256, 0, stream>>>(XB, eidx, etype, edge_emb, irow, ielist, Zb);
        gemm_bf<1, 0, 0, 1, 0><<<g1, 256, 0, stream>>>(Zb, gW1T, gb1, nullptr, T1, nullptr, 128);
        gemm_bf<0, 1, 1, 1, 1><<<g1, 256, 0, stream>>>(T1, gW2T, gb2, XB, Zf, STATS, 128);
        bn_finalize<<<1, 128, 0, stream>>>(STATS, n1_g + l * CC, n1_b + l * CC, SCOFF, 128, invn);

        // ---- attention ----
        gemm_bf<0, 0, 0, 1, 0><<<g3, 256, 0, stream>>>(XB, inWT, inb, nullptr, Rq, nullptr, 384);
        attn_mfma<<<BB * 2, 256, 0, stream>>>(Rq, T1);
        gemm_bf<0, 1, 1, 1, 1><<<g1, 256, 0, stream>>>(T1, oWT, ob, XB, HAf, STATS + 256, 128);
        bn_finalize<<<1, 128, 0, stream>>>(STATS + 256, n2_g + l * CC, n2_b + l * CC, SCOFF + 256, 128, invn);

        // ---- combine + FFN ----
        combine2<<<EW16, 256, 0, stream>>>(Zf, HAf, SCOFF, OUTb);
        gemm_bf<1, 0, 0, 1, 0><<<g2, 256, 0, stream>>>(OUTb, mW1T, mb1, nullptr, T2, nullptr, 256);
        gemm_bf<0, 1, 1, 2, 1><<<g1, 256, 0, stream>>>(T2, mW2T, mb2, OUTb, Zf, STATS + 512, 128);
        bn_finalize<<<1, 128, 0, stream>>>(STATS + 512, n3_g + l * CC, n3_b + l * CC, SCOFF, 128, invn);
        if (l < LL - 1)
            bn_apply_b<<<EW16, 256, 0, stream>>>(Zf, SCOFF, XB);
        else
            bn_apply_f<<<EW16, 256, 0, stream>>>(Zf, SCOFF, outF);
    }
}